// Round 3
// baseline (865.910 us; speedup 1.0000x reference)
//
#include <hip/hip_runtime.h>
#include <hip/hip_bf16.h>
#include <cstdint>
#include <cstddef>

// Problem constants (B,H,S,D) = (2,16,2048,64)
#define BB 2
#define HH 16
#define SS 2048
#define DD 64
#define NBH (BB * HH)
#define BQ 16          // query rows per workgroup
#define NWAVES 8       // waves per workgroup
#define BLK 512        // threads per workgroup
#define CW 512         // probs chunk width (cols)
#define NCHUNK (SS / CW)
#define CSTRIDE 516    // padded fp32 LDS row stride (bank offset 4/row)

typedef __attribute__((ext_vector_type(8))) short bf16x8;
typedef __attribute__((ext_vector_type(4))) float f32x4;
typedef __attribute__((ext_vector_type(4))) unsigned short us4;

// LDS-only barrier: wait for this wave's LDS ops, then s_barrier — WITHOUT
// the vmcnt(0) drain that __syncthreads() emits (keeps NT probs stores in
// flight across chunk boundaries).
#define LGKM_BAR() asm volatile("s_waitcnt lgkmcnt(0)\n\ts_barrier" ::: "memory")

__device__ __forceinline__ unsigned short f2bf(float x) {
  union { float f; uint32_t u; } c;
  c.f = x;
  uint32_t u = c.u;
  uint32_t r = (u + 0x7FFFu + ((u >> 16) & 1u)) >> 16;  // RNE fp32->bf16
  return (unsigned short)r;
}

// ---- pre-pass 1: q,k fp32 -> bf16 (elementwise) -------------------------
__global__ __launch_bounds__(256) void cvt_qk_kernel(
    const float* __restrict__ q, const float* __restrict__ k,
    unsigned short* __restrict__ qb, unsigned short* __restrict__ kb) {
  size_t i = ((size_t)blockIdx.x * 256 + threadIdx.x) * 4;
  float4 a = *(const float4*)(q + i);
  float4 b = *(const float4*)(k + i);
  us4 qa = {f2bf(a.x), f2bf(a.y), f2bf(a.z), f2bf(a.w)};
  us4 ka = {f2bf(b.x), f2bf(b.y), f2bf(b.z), f2bf(b.w)};
  *(us4*)(qb + i) = qa;
  *(us4*)(kb + i) = ka;
}

// ---- pre-pass 2: v fp32 [bh][s][d] -> vt bf16 [bh][d][s] ----------------
// (round-1 scalar-store form; round-2 us4 variant regressed)
__global__ __launch_bounds__(256) void cvt_vt_kernel(
    const float* __restrict__ v, unsigned short* __restrict__ vt) {
  __shared__ unsigned short t[64][65];
  const int tid = threadIdx.x;
  const int bh = blockIdx.y;
  const int s0 = blockIdx.x * 64;
  const float* vb = v + ((size_t)bh * SS + s0) * DD;
#pragma unroll
  for (int it = 0; it < 16; ++it) {
    int idx = it * 256 + tid;
    int s = idx >> 6, d = idx & 63;
    t[s][d] = f2bf(vb[idx]);
  }
  __syncthreads();
  unsigned short* vo = vt + (size_t)bh * DD * SS + s0;
#pragma unroll
  for (int it = 0; it < 16; ++it) {
    int idx = it * 256 + tid;
    int d = idx >> 6, s = idx & 63;
    vo[(size_t)d * SS + s] = t[s][d];
  }
}

// ---- main fused attention kernel ----------------------------------------
// grid: (SS/BQ, NBH), block: 512 (8 waves).
// TWO-PASS (recompute) softmax: leaky softmax with m=0 needs only the
// row-sum before scaling, so pass 1 computes QK^T tiles, exps them into a
// row-sum and DISCARDS them (live set: 16 regs, not 64). Pass 2 recomputes
// each 512-col chunk (K is L2-hot), scales, fills LDS, runs PV + NT store.
// This cuts VGPR+AGPR from ~150 (1 block/CU, barrier convoy, 85% stall) to
// <=128 so 2 blocks/CU co-reside and phases overlap across blocks.
__global__ __launch_bounds__(BLK, 4) void attn_kernel(
    const unsigned short* __restrict__ qb,
    const unsigned short* __restrict__ kb,
    const unsigned short* __restrict__ vt,
    const float* __restrict__ cst,
    const int* __restrict__ mask,
    float* __restrict__ out,
    float* __restrict__ probs) {
  __shared__ float pch[BQ][CSTRIDE];      // 33 KB fp32 probs chunk
  __shared__ float stats[NWAVES][BQ];
  __shared__ float rowinv[BQ];

  const int tid = threadIdx.x;
  const int wave = tid >> 6;
  const int lane = tid & 63;
  const int quad = lane >> 4;
  const int l16 = lane & 15;
  const int bh = blockIdx.y;
  const int bidx = bh >> 4;  // batch
  const int h = bh & 15;
  const int q0 = blockIdx.x * BQ;

  // Q fragments (A operand: A[m=lane&15][k=quad*8+j])
  const unsigned short* qrow = qb + ((size_t)bh * SS + q0 + l16) * DD + quad * 8;
  bf16x8 aq0 = *(const bf16x8*)(qrow);
  bf16x8 aq1 = *(const bf16x8*)(qrow + 32);

  const unsigned short* kbase = kb + (size_t)bh * SS * DD;
  const int* mrow = mask + bidx * SS;

  // ---- pass 1: QK^T + exp + row-sum, tiles discarded ----
  // C/D layout: col = col0 + l16, row = quad*4 + r
  float rsum[4] = {0.f, 0.f, 0.f, 0.f};
#pragma unroll
  for (int t = 0; t < 16; ++t) {
    int col0 = (wave + 8 * t) * 16;
    const unsigned short* krow = kbase + (size_t)(col0 + l16) * DD + quad * 8;
    bf16x8 bk0 = *(const bf16x8*)(krow);
    bf16x8 bk1 = *(const bf16x8*)(krow + 32);
    f32x4 c = {0.f, 0.f, 0.f, 0.f};
    c = __builtin_amdgcn_mfma_f32_16x16x32_bf16(aq0, bk0, c, 0, 0, 0);
    c = __builtin_amdgcn_mfma_f32_16x16x32_bf16(aq1, bk1, c, 0, 0, 0);
    int mk = mrow[col0 + l16];
#pragma unroll
    for (int r = 0; r < 4; ++r)
      rsum[r] += mk ? 0.0f : __expf(c[r] * 0.125f);
  }
#pragma unroll
  for (int off = 8; off >= 1; off >>= 1)
#pragma unroll
    for (int r = 0; r < 4; ++r)
      rsum[r] += __shfl_xor(rsum[r], off, 64);
  if (l16 == 0)
#pragma unroll
    for (int r = 0; r < 4; ++r) stats[wave][quad * 4 + r] = rsum[r];
  __syncthreads();
  if (tid < BQ) {
    float s = 0.f;
#pragma unroll
    for (int w = 0; w < NWAVES; ++w) s += stats[w][tid];
    float denom = s + __expf(cst[h]) * (float)SS;  // leaky term, m=0
    rowinv[tid] = 1.0f / denom;
  }
  __syncthreads();
  float inv[4];
#pragma unroll
  for (int r = 0; r < 4; ++r) inv[r] = rowinv[quad * 4 + r];

  // ---- pass 2 per chunk: recompute -> LDS fill -> PV -> NT probs store ----
  f32x4 acco[4];
#pragma unroll
  for (int dt = 0; dt < 4; ++dt) acco[dt] = (f32x4){0.f, 0.f, 0.f, 0.f};
  const unsigned short* vbase = vt + (size_t)bh * DD * SS;
#pragma unroll
  for (int c = 0; c < NCHUNK; ++c) {
    // prefetch V for ks=0 (latency hides under recompute + fill)
    const int kg0 = c * CW + wave * 64 + quad * 8;
    bf16x8 v0[4];
#pragma unroll
    for (int dt = 0; dt < 4; ++dt)
      v0[dt] = *(const bf16x8*)(vbase + (size_t)(dt * 16 + l16) * SS + kg0);

    if (c) LGKM_BAR();  // protect pch reuse from previous chunk's reads
    // recompute 4 tiles of this chunk, scale, write straight to LDS
#pragma unroll
    for (int tt = 0; tt < 4; ++tt) {
      int t = c * 4 + tt;
      int col0 = (wave + 8 * t) * 16;
      const unsigned short* krow = kbase + (size_t)(col0 + l16) * DD + quad * 8;
      bf16x8 bk0 = *(const bf16x8*)(krow);
      bf16x8 bk1 = *(const bf16x8*)(krow + 32);
      f32x4 ct = {0.f, 0.f, 0.f, 0.f};
      ct = __builtin_amdgcn_mfma_f32_16x16x32_bf16(aq0, bk0, ct, 0, 0, 0);
      ct = __builtin_amdgcn_mfma_f32_16x16x32_bf16(aq1, bk1, ct, 0, 0, 0);
      int mk = mrow[col0 + l16];
      int lcol = tt * 128 + wave * 16 + l16;
#pragma unroll
      for (int r = 0; r < 4; ++r) {
        float e = mk ? 0.0f : __expf(ct[r] * 0.125f) * inv[r];
        pch[quad * 4 + r][lcol] = e;
      }
    }
    LGKM_BAR();

    // PV ks=0
    {
      const f32x4* ap4 = (const f32x4*)&pch[l16][wave * 64 + quad * 8];
      f32x4 p0 = ap4[0], p1 = ap4[1];
      union { bf16x8 v8; uint32_t u[4]; } apu;
      asm("v_cvt_pk_bf16_f32 %0, %1, %2" : "=v"(apu.u[0]) : "v"(p0.x), "v"(p0.y));
      asm("v_cvt_pk_bf16_f32 %0, %1, %2" : "=v"(apu.u[1]) : "v"(p0.z), "v"(p0.w));
      asm("v_cvt_pk_bf16_f32 %0, %1, %2" : "=v"(apu.u[2]) : "v"(p1.x), "v"(p1.y));
      asm("v_cvt_pk_bf16_f32 %0, %1, %2" : "=v"(apu.u[3]) : "v"(p1.z), "v"(p1.w));
      bf16x8 ap = apu.v8;
      // prefetch V for ks=1 while ks=0 MFMAs issue
      bf16x8 v1[4];
#pragma unroll
      for (int dt = 0; dt < 4; ++dt)
        v1[dt] = *(const bf16x8*)(vbase + (size_t)(dt * 16 + l16) * SS + kg0 + 32);
#pragma unroll
      for (int dt = 0; dt < 4; ++dt)
        acco[dt] = __builtin_amdgcn_mfma_f32_16x16x32_bf16(ap, v0[dt], acco[dt], 0, 0, 0);

      // PV ks=1
      const f32x4* bp4 = (const f32x4*)&pch[l16][wave * 64 + 32 + quad * 8];
      f32x4 q0v = bp4[0], q1v = bp4[1];
      union { bf16x8 v8; uint32_t u[4]; } bpu;
      asm("v_cvt_pk_bf16_f32 %0, %1, %2" : "=v"(bpu.u[0]) : "v"(q0v.x), "v"(q0v.y));
      asm("v_cvt_pk_bf16_f32 %0, %1, %2" : "=v"(bpu.u[1]) : "v"(q0v.z), "v"(q0v.w));
      asm("v_cvt_pk_bf16_f32 %0, %1, %2" : "=v"(bpu.u[2]) : "v"(q1v.x), "v"(q1v.y));
      asm("v_cvt_pk_bf16_f32 %0, %1, %2" : "=v"(bpu.u[3]) : "v"(q1v.z), "v"(q1v.w));
      bf16x8 bp = bpu.v8;
#pragma unroll
      for (int dt = 0; dt < 4; ++dt)
        acco[dt] = __builtin_amdgcn_mfma_f32_16x16x32_bf16(bp, v1[dt], acco[dt], 0, 0, 0);
    }

    // nontemporal coalesced probs store (write-once data: bypass L2)
#pragma unroll
    for (int i = 0; i < 4; ++i) {
      int f = i * BLK + tid;
      int row = f >> 7, c4 = f & 127;
      f32x4 val = *(const f32x4*)&pch[row][c4 * 4];
      f32x4* dst = (f32x4*)(probs + (size_t)bh * SS * SS +
                            (size_t)(q0 + row) * SS + c * CW) + c4;
      __builtin_nontemporal_store(val, dst);
    }
  }

  // ---- cross-wave reduction of out partials (reuse pch: 8192 floats) ----
  LGKM_BAR();  // probs stores may still be in flight — don't drain them
  float* outp = &pch[0][0];
#pragma unroll
  for (int dt = 0; dt < 4; ++dt)
#pragma unroll
    for (int r = 0; r < 4; ++r)
      outp[((wave * BQ) + quad * 4 + r) * DD + dt * 16 + l16] = acco[dt][r];
  LGKM_BAR();
  for (int e = tid; e < BQ * DD; e += BLK) {
    int row = e >> 6, col = e & 63;
    float s = 0.f;
#pragma unroll
    for (int w = 0; w < NWAVES; ++w) s += outp[(w * BQ + row) * DD + col];
    out[((size_t)bh * SS + q0 + row) * DD + col] = s;
  }
}

extern "C" void kernel_launch(void* const* d_in, const int* in_sizes, int n_in,
                              void* d_out, int out_size, void* d_ws, size_t ws_size,
                              hipStream_t stream) {
  const float* q = (const float*)d_in[0];
  const float* k = (const float*)d_in[1];
  const float* v = (const float*)d_in[2];
  const float* cst = (const float*)d_in[3];
  const int* mask = (const int*)d_in[4];

  float* out = (float*)d_out;
  float* probs = out + (size_t)NBH * SS * DD;  // tuple output: out then probs

  const size_t nelem = (size_t)NBH * SS * DD;
  unsigned short* qb = (unsigned short*)d_ws;
  unsigned short* kb = qb + nelem;
  unsigned short* vt = kb + nelem;

  cvt_qk_kernel<<<dim3((unsigned)(nelem / (256 * 4))), 256, 0, stream>>>(q, k, qb, kb);
  cvt_vt_kernel<<<dim3(SS / 64, NBH), 256, 0, stream>>>(v, vt);

  attn_kernel<<<dim3(SS / BQ, NBH), BLK, 0, stream>>>(qb, kb, vt, cst, mask, out, probs);
}

// Round 4
// 849.708 us; speedup vs baseline: 1.0191x; 1.0191x over previous
//
#include <hip/hip_runtime.h>
#include <hip/hip_bf16.h>
#include <cstdint>
#include <cstddef>

// Problem constants (B,H,S,D) = (2,16,2048,64)
#define BB 2
#define HH 16
#define SS 2048
#define DD 64
#define NBH (BB * HH)
#define BQ 16          // query rows per workgroup
#define NWAVES 8       // waves per workgroup
#define BLK 512        // threads per workgroup
#define CW 256         // probs chunk width (cols)
#define NCHUNK (SS / CW)   // 8
#define CSTRIDE 260    // padded fp32 LDS row stride

typedef __attribute__((ext_vector_type(8))) short bf16x8;
typedef __attribute__((ext_vector_type(4))) float f32x4;
typedef __attribute__((ext_vector_type(4))) unsigned short us4;

// LDS-only barrier: wait this wave's LDS ops then s_barrier — WITHOUT the
// vmcnt(0) drain of __syncthreads(), so in-flight probs stores are never
// drained at chunk boundaries.
#define LGKM_BAR() asm volatile("s_waitcnt lgkmcnt(0)\n\ts_barrier" ::: "memory")

__device__ __forceinline__ unsigned short f2bf(float x) {
  union { float f; uint32_t u; } c;
  c.f = x;
  uint32_t u = c.u;
  uint32_t r = (u + 0x7FFFu + ((u >> 16) & 1u)) >> 16;  // RNE fp32->bf16
  return (unsigned short)r;
}

// ---- pre-pass 1: q,k fp32 -> bf16 (elementwise) -------------------------
__global__ __launch_bounds__(256) void cvt_qk_kernel(
    const float* __restrict__ q, const float* __restrict__ k,
    unsigned short* __restrict__ qb, unsigned short* __restrict__ kb) {
  size_t i = ((size_t)blockIdx.x * 256 + threadIdx.x) * 4;
  float4 a = *(const float4*)(q + i);
  float4 b = *(const float4*)(k + i);
  us4 qa = {f2bf(a.x), f2bf(a.y), f2bf(a.z), f2bf(a.w)};
  us4 ka = {f2bf(b.x), f2bf(b.y), f2bf(b.z), f2bf(b.w)};
  *(us4*)(qb + i) = qa;
  *(us4*)(kb + i) = ka;
}

// ---- pre-pass 2: v fp32 [bh][s][d] -> vt bf16 [bh][d][s] ----------------
__global__ __launch_bounds__(256) void cvt_vt_kernel(
    const float* __restrict__ v, unsigned short* __restrict__ vt) {
  __shared__ unsigned short t[64][65];
  const int tid = threadIdx.x;
  const int bh = blockIdx.y;
  const int s0 = blockIdx.x * 64;
  const float* vb = v + ((size_t)bh * SS + s0) * DD;
#pragma unroll
  for (int it = 0; it < 16; ++it) {
    int idx = it * 256 + tid;
    int s = idx >> 6, d = idx & 63;
    t[s][d] = f2bf(vb[idx]);
  }
  __syncthreads();
  unsigned short* vo = vt + (size_t)bh * DD * SS + s0;
#pragma unroll
  for (int it = 0; it < 16; ++it) {
    int idx = it * 256 + tid;
    int d = idx >> 6, s = idx & 63;
    vo[(size_t)d * SS + s] = t[s][d];
  }
}

// ---- main fused attention kernel ----------------------------------------
// grid: (SS/BQ, NBH), block: 512 (8 waves).
// Two-pass leaky softmax (m=0); pass 2 is software-pipelined so that NO
// load is ever issued after an unretired probs store (vmcnt retires in
// issue order — a load younger than a store cannot "retire" in counter
// terms until the store drains to HBM; r2/r3 serialized on exactly that).
// Per chunk: [bar][recompute from kpref -> pch][bar][PV from pch+vpref]
// [sreg<-pch][prefetch K/V(c+1)][sched_barrier][NT stores from sreg].
__global__ __launch_bounds__(BLK, 4) void attn_kernel(
    const unsigned short* __restrict__ qb,
    const unsigned short* __restrict__ kb,
    const unsigned short* __restrict__ vt,
    const float* __restrict__ cst,
    const int* __restrict__ mask,
    float* __restrict__ out,
    float* __restrict__ probs) {
  __shared__ float pch[BQ][CSTRIDE];      // 16.6 KB fp32 probs chunk
  __shared__ float stats[NWAVES][BQ];
  __shared__ float rowinv[BQ];

  const int tid = threadIdx.x;
  const int wave = tid >> 6;
  const int lane = tid & 63;
  const int quad = lane >> 4;
  const int l16 = lane & 15;
  const int bh = blockIdx.y;
  const int bidx = bh >> 4;  // batch
  const int h = bh & 15;
  const int q0 = blockIdx.x * BQ;

  // Q fragments (A operand: A[m=lane&15][k=quad*8+j])
  const unsigned short* qrow = qb + ((size_t)bh * SS + q0 + l16) * DD + quad * 8;
  bf16x8 aq0 = *(const bf16x8*)(qrow);
  bf16x8 aq1 = *(const bf16x8*)(qrow + 32);

  const unsigned short* kbase = kb + (size_t)bh * SS * DD;
  const int* mrow = mask + bidx * SS;

  // ---- pass 1: QK^T + exp + row-sum; mask folded into per-lane bitmask ----
  // C/D layout: col = col0 + l16, row = quad*4 + r
  float rsum[4] = {0.f, 0.f, 0.f, 0.f};
  unsigned int mbits = 0;
#pragma unroll
  for (int t = 0; t < 16; ++t) {
    int col0 = (wave + 8 * t) * 16;
    const unsigned short* krow = kbase + (size_t)(col0 + l16) * DD + quad * 8;
    bf16x8 bk0 = *(const bf16x8*)(krow);
    bf16x8 bk1 = *(const bf16x8*)(krow + 32);
    f32x4 c = {0.f, 0.f, 0.f, 0.f};
    c = __builtin_amdgcn_mfma_f32_16x16x32_bf16(aq0, bk0, c, 0, 0, 0);
    c = __builtin_amdgcn_mfma_f32_16x16x32_bf16(aq1, bk1, c, 0, 0, 0);
    int mk = mrow[col0 + l16];
    mbits |= (unsigned)(mk & 1) << t;
#pragma unroll
    for (int r = 0; r < 4; ++r)
      rsum[r] += mk ? 0.0f : __expf(c[r] * 0.125f);
  }
#pragma unroll
  for (int off = 8; off >= 1; off >>= 1)
#pragma unroll
    for (int r = 0; r < 4; ++r)
      rsum[r] += __shfl_xor(rsum[r], off, 64);
  if (l16 == 0)
#pragma unroll
    for (int r = 0; r < 4; ++r) stats[wave][quad * 4 + r] = rsum[r];
  __syncthreads();
  if (tid < BQ) {
    float s = 0.f;
#pragma unroll
    for (int w = 0; w < NWAVES; ++w) s += stats[w][tid];
    float denom = s + __expf(cst[h]) * (float)SS;  // leaky term, m=0
    rowinv[tid] = 1.0f / denom;
  }
  __syncthreads();
  float inv[4];
#pragma unroll
  for (int r = 0; r < 4; ++r) inv[r] = rowinv[quad * 4 + r];

  // ---- pass 2: pipelined recompute -> LDS -> PV -> NT stores ----
  f32x4 acco[4];
#pragma unroll
  for (int dt = 0; dt < 4; ++dt) acco[dt] = (f32x4){0.f, 0.f, 0.f, 0.f};
  const unsigned short* vbase = vt + (size_t)bh * DD * SS;

  bf16x8 kpref[4];     // K operands for current chunk (2 tiles x 2)
  bf16x8 vpref[4];     // V operands for current chunk (4 dt)
  f32x4 sreg[2][2];    // store-data double buffer (2-chunk WAR slack)

  // prologue: K(0), V(0) — issued before ANY store exists
#pragma unroll
  for (int tt = 0; tt < 2; ++tt) {
    int col0 = (8 * tt + wave) * 16;
    const unsigned short* krow = kbase + (size_t)(col0 + l16) * DD + quad * 8;
    kpref[2 * tt] = *(const bf16x8*)(krow);
    kpref[2 * tt + 1] = *(const bf16x8*)(krow + 32);
  }
#pragma unroll
  for (int dt = 0; dt < 4; ++dt)
    vpref[dt] = *(const bf16x8*)(vbase + (size_t)(dt * 16 + l16) * SS +
                                 wave * 32 + quad * 8);

#pragma unroll
  for (int c = 0; c < NCHUNK; ++c) {
    if (c) LGKM_BAR();  // protect pch reuse from previous chunk's reads
    // recompute 2 tiles from kpref, scale, write to LDS
#pragma unroll
    for (int tt = 0; tt < 2; ++tt) {
      f32x4 ct = {0.f, 0.f, 0.f, 0.f};
      ct = __builtin_amdgcn_mfma_f32_16x16x32_bf16(aq0, kpref[2 * tt], ct, 0, 0, 0);
      ct = __builtin_amdgcn_mfma_f32_16x16x32_bf16(aq1, kpref[2 * tt + 1], ct, 0, 0, 0);
      int mk = (int)((mbits >> (2 * c + tt)) & 1u);
      int lcol = (8 * tt + wave) * 16 + l16;
#pragma unroll
      for (int r = 0; r < 4; ++r)
        pch[quad * 4 + r][lcol] = mk ? 0.0f : __expf(ct[r] * 0.125f) * inv[r];
    }
    LGKM_BAR();

    // PV: P from LDS, cvt to bf16, MFMA with prefetched V
    {
      const f32x4* ap4 = (const f32x4*)&pch[l16][wave * 32 + quad * 8];
      f32x4 p0 = ap4[0], p1 = ap4[1];
      union { bf16x8 v8; uint32_t u[4]; } apu;
      asm("v_cvt_pk_bf16_f32 %0, %1, %2" : "=v"(apu.u[0]) : "v"(p0.x), "v"(p0.y));
      asm("v_cvt_pk_bf16_f32 %0, %1, %2" : "=v"(apu.u[1]) : "v"(p0.z), "v"(p0.w));
      asm("v_cvt_pk_bf16_f32 %0, %1, %2" : "=v"(apu.u[2]) : "v"(p1.x), "v"(p1.y));
      asm("v_cvt_pk_bf16_f32 %0, %1, %2" : "=v"(apu.u[3]) : "v"(p1.z), "v"(p1.w));
      bf16x8 ap = apu.v8;
#pragma unroll
      for (int dt = 0; dt < 4; ++dt)
        acco[dt] = __builtin_amdgcn_mfma_f32_16x16x32_bf16(ap, vpref[dt], acco[dt], 0, 0, 0);
    }

    // store-data LDS reads (latency hides under prefetch issue below)
#pragma unroll
    for (int i = 0; i < 2; ++i) {
      int f = i * BLK + tid;
      int row = f >> 6, c4 = f & 63;
      sreg[c & 1][i] = *(const f32x4*)&pch[row][c4 * 4];
    }

    // prefetch next chunk's K and V — ISSUED BEFORE THIS CHUNK'S STORES,
    // so their consuming waits never require store retirement (vmcnt(2)).
    if (c + 1 < NCHUNK) {
#pragma unroll
      for (int tt = 0; tt < 2; ++tt) {
        int col0 = (16 * (c + 1) + 8 * tt + wave) * 16;
        const unsigned short* krow = kbase + (size_t)(col0 + l16) * DD + quad * 8;
        kpref[2 * tt] = *(const bf16x8*)(krow);
        kpref[2 * tt + 1] = *(const bf16x8*)(krow + 32);
      }
      int kg = (c + 1) * CW + wave * 32 + quad * 8;
#pragma unroll
      for (int dt = 0; dt < 4; ++dt)
        vpref[dt] = *(const bf16x8*)(vbase + (size_t)(dt * 16 + l16) * SS + kg);
    }
    __builtin_amdgcn_sched_barrier(0);  // pin: prefetch issues before stores

    // NT probs stores last — nothing younger in this chunk waits on them
#pragma unroll
    for (int i = 0; i < 2; ++i) {
      int f = i * BLK + tid;
      int row = f >> 6, c4 = f & 63;
      f32x4* dst = (f32x4*)(probs + (size_t)bh * SS * SS +
                            (size_t)(q0 + row) * SS + c * CW) + c4;
      __builtin_nontemporal_store(sreg[c & 1][i], dst);
    }
  }

  // ---- cross-wave reduction of out partials (reuse pch: 4160 floats) ----
  LGKM_BAR();  // probs stores may still be in flight — don't drain them
  float* outp = &pch[0][0];
  // 8 waves x 16 rows x 16 cols partials won't fit as before (pch smaller);
  // reduce in two half-d passes: cols [0,32) then [32,64)
#pragma unroll
  for (int half = 0; half < 2; ++half) {
    if (half) LGKM_BAR();
#pragma unroll
    for (int dt = 0; dt < 2; ++dt)
#pragma unroll
      for (int r = 0; r < 4; ++r)
        outp[((wave * BQ) + quad * 4 + r) * 32 + dt * 16 + l16] =
            acco[half * 2 + dt][r];
    LGKM_BAR();
    for (int e = tid; e < BQ * 32; e += BLK) {
      int row = e >> 5, col = e & 31;
      float s = 0.f;
#pragma unroll
      for (int w = 0; w < NWAVES; ++w) s += outp[(w * BQ + row) * 32 + col];
      out[((size_t)bh * SS + q0 + row) * DD + half * 32 + col] = s;
    }
  }
}

extern "C" void kernel_launch(void* const* d_in, const int* in_sizes, int n_in,
                              void* d_out, int out_size, void* d_ws, size_t ws_size,
                              hipStream_t stream) {
  const float* q = (const float*)d_in[0];
  const float* k = (const float*)d_in[1];
  const float* v = (const float*)d_in[2];
  const float* cst = (const float*)d_in[3];
  const int* mask = (const int*)d_in[4];

  float* out = (float*)d_out;
  float* probs = out + (size_t)NBH * SS * DD;  // tuple output: out then probs

  const size_t nelem = (size_t)NBH * SS * DD;
  unsigned short* qb = (unsigned short*)d_ws;
  unsigned short* kb = qb + nelem;
  unsigned short* vt = kb + nelem;

  cvt_qk_kernel<<<dim3((unsigned)(nelem / (256 * 4))), 256, 0, stream>>>(q, k, qb, kb);
  cvt_vt_kernel<<<dim3(SS / 64, NBH), 256, 0, stream>>>(v, vt);

  attn_kernel<<<dim3(SS / BQ, NBH), BLK, 0, stream>>>(qb, kb, vt, cst, mask, out, probs);
}